// Round 1
// baseline (425.761 us; speedup 1.0000x reference)
//
#include <hip/hip_runtime.h>
#include <cstdint>
#include <cstddef>

#define LSEQ 4096
#define DMODEL 1152
#define NH 16
#define HD 72
#define HP96 96
#define HP80 80
#define NQKV 3456

typedef unsigned short u16;
typedef __attribute__((ext_vector_type(4))) float f32x4;
typedef _Float16 f16x8 __attribute__((ext_vector_type(8), may_alias));
typedef unsigned short us8 __attribute__((ext_vector_type(8), may_alias));
typedef unsigned short us4 __attribute__((ext_vector_type(4), may_alias));

static __device__ __forceinline__ u16 f2h(float f) {
  _Float16 h = (_Float16)f;
  return __builtin_bit_cast(u16, h);
}
static __device__ __forceinline__ float h2f(u16 b) {
  return (float)__builtin_bit_cast(_Float16, b);
}

// ---------------- f32 -> f16 elementwise ----------------
__global__ void k_cvt_f16(const float* __restrict__ src, u16* __restrict__ dst, int n4) {
  int i = blockIdx.x * blockDim.x + threadIdx.x;
  int stride = gridDim.x * blockDim.x;
  for (; i < n4; i += stride) {
    float4 v = ((const float4*)src)[i];
    us4 o; o[0] = f2h(v.x); o[1] = f2h(v.y); o[2] = f2h(v.z); o[3] = f2h(v.w);
    ((us4*)dst)[i] = o;
  }
}

// ---------------- dst[n][k] = (f16) src[k][n]  (weight transpose) ----------------
__global__ void k_transp_w(const float* __restrict__ src, u16* __restrict__ dst, int K, int N) {
  __shared__ float tile[32][33];
  int tx = threadIdx.x & 31, ty = threadIdx.x >> 5;
  int n0 = blockIdx.x * 32, k0 = blockIdx.y * 32;
#pragma unroll
  for (int j = 0; j < 4; ++j)
    tile[ty + j * 8][tx] = src[(size_t)(k0 + ty + j * 8) * N + n0 + tx];
  __syncthreads();
#pragma unroll
  for (int j = 0; j < 4; ++j)
    dst[(size_t)(n0 + ty + j * 8) * K + k0 + tx] = f2h(tile[tx][ty + j * 8]);
}

// ---------------- C[M][N] = A[M][K] @ Bt[N][K]^T (+bias), f16 in, f16/f32 out ----------------
// 128x128 tile, BK=32, 4 waves (2x2 of 64x64), 16x16x32 f16 MFMA.
template <bool OUTF32>
__global__ __launch_bounds__(256) void k_gemm_bt(
    const u16* __restrict__ A, const u16* __restrict__ Bt,
    const float* __restrict__ bias, void* __restrict__ Cout,
    int M, int N, int K) {
  __shared__ __align__(16) u16 sA[128][40];  // +8 pad: 2-way bank aliasing only
  __shared__ __align__(16) u16 sB[128][40];
  int t = threadIdx.x;
  int l = t & 63, w = t >> 6, lo = l & 15, hi = l >> 4;
  int m0 = blockIdx.y * 128, n0 = blockIdx.x * 128;
  int wm = (w >> 1) * 64, wn = (w & 1) * 64;
  int sr = t >> 1, sh = (t & 1) * 16;
  const u16* pa = A + (size_t)(m0 + sr) * K + sh;
  const u16* pb = Bt + (size_t)(n0 + sr) * K + sh;
  f32x4 acc[4][4] = {};
  us8 ra0 = *(const us8*)(pa), ra1 = *(const us8*)(pa + 8);
  us8 rb0 = *(const us8*)(pb), rb1 = *(const us8*)(pb + 8);
  int nk = K >> 5;
  for (int ks = 0; ks < nk; ++ks) {
    __syncthreads();
    *(us8*)&sA[sr][sh] = ra0; *(us8*)&sA[sr][sh + 8] = ra1;
    *(us8*)&sB[sr][sh] = rb0; *(us8*)&sB[sr][sh + 8] = rb1;
    if (ks + 1 < nk) {  // prefetch next tile into regs; latency hides under MFMA
      int off = (ks + 1) * 32;
      ra0 = *(const us8*)(pa + off); ra1 = *(const us8*)(pa + off + 8);
      rb0 = *(const us8*)(pb + off); rb1 = *(const us8*)(pb + off + 8);
    }
    __syncthreads();
    f16x8 af[4], bf[4];
#pragma unroll
    for (int mi = 0; mi < 4; ++mi) af[mi] = *(const f16x8*)&sA[wm + mi * 16 + lo][hi * 8];
#pragma unroll
    for (int ni = 0; ni < 4; ++ni) bf[ni] = *(const f16x8*)&sB[wn + ni * 16 + lo][hi * 8];
#pragma unroll
    for (int mi = 0; mi < 4; ++mi)
#pragma unroll
      for (int ni = 0; ni < 4; ++ni)
        acc[mi][ni] = __builtin_amdgcn_mfma_f32_16x16x32_f16(af[mi], bf[ni], acc[mi][ni], 0, 0, 0);
  }
#pragma unroll
  for (int mi = 0; mi < 4; ++mi)
#pragma unroll
    for (int ni = 0; ni < 4; ++ni) {
      int row = m0 + wm + mi * 16 + hi * 4;
      int col = n0 + wn + ni * 16 + lo;
      float bv = bias ? bias[col] : 0.0f;
#pragma unroll
      for (int rr = 0; rr < 4; ++rr) {
        float v = acc[mi][ni][rr] + bv;
        if (OUTF32) ((float*)Cout)[(size_t)(row + rr) * N + col] = v;
        else        ((u16*)Cout)[(size_t)(row + rr) * N + col] = f2h(v);
      }
    }
}

// ---------------- per-token: +bias, per-head RMSNorm, 2D RoPE, scatter to head-major ----------------
__global__ __launch_bounds__(256) void k_norm_rope(
    const u16* __restrict__ qkv,
    const float* __restrict__ q_b, const float* __restrict__ kv_b,
    const float* __restrict__ q_s, const float* __restrict__ k_s,
    u16* __restrict__ qp, u16* __restrict__ kp, u16* __restrict__ vn) {
  __shared__ float s_q[DMODEL], s_k[DMODEL], s_v[DMODEL];
  __shared__ float cs[4][18];  // [cr, sr, cc, sc]
  int t = threadIdx.x;
  int tok = blockIdx.x;
  if (t < 36) {
    int i = t < 18 ? t : t - 18;
    float f = exp2f(-(float)i * (6.6438561897747247f / 9.0f));  // 100^(-i/9)
    float pos = (t < 18) ? (float)(tok >> 6) : (float)(tok & 63);
    float s, c;
    sincosf(pos * f, &s, &c);
    if (t < 18) { cs[0][i] = c; cs[1][i] = s; }
    else        { cs[2][i] = c; cs[3][i] = s; }
  }
  const u16* rowp = qkv + (size_t)tok * NQKV;
  for (int idx = t; idx < DMODEL; idx += 256) {
    s_q[idx] = h2f(rowp[idx]) + q_b[idx];
    s_k[idx] = h2f(rowp[DMODEL + idx]) + kv_b[idx];
    s_v[idx] = h2f(rowp[2 * DMODEL + idx]) + kv_b[DMODEL + idx];
  }
  __syncthreads();
  int h = t >> 4, sub = t & 15;  // 16 threads per head
  int base = h * HD;
  float aq = 0, ak = 0, av = 0;
#pragma unroll
  for (int j = 0; j < 5; ++j) {
    int idx = sub + 16 * j;
    if (idx < HD) {
      float a = s_q[base + idx], b = s_k[base + idx], c = s_v[base + idx];
      aq += a * a; ak += b * b; av += c * c;
    }
  }
#pragma unroll
  for (int m = 1; m <= 8; m <<= 1) {
    aq += __shfl_xor(aq, m, 64);
    ak += __shfl_xor(ak, m, 64);
    av += __shfl_xor(av, m, 64);
  }
  float rq = rsqrtf(aq / 72.f + 1e-6f);
  float rk = rsqrtf(ak / 72.f + 1e-6f);
  float rv = rsqrtf(av / 72.f + 1e-6f);
  size_t ob96 = ((size_t)h * LSEQ + tok) * HP96;
  size_t ob80 = ((size_t)h * LSEQ + tok) * HP80;
#pragma unroll
  for (int j = 0; j < 6; ++j) {
    int idx = sub + 16 * j;  // 0..95
    float oq = 0.f, ok = 0.f;
    if (idx < HD) {
      int sec = idx >= 36;          // 0: rows angle, 1: cols angle
      int loc = idx - sec * 36;
      int i = loc >= 18 ? loc - 18 : loc;
      float c = cs[sec * 2 + 0][i], s = cs[sec * 2 + 1][i];
      int p1 = sec * 36 + i, p2 = p1 + 18;
      float q1 = s_q[base + p1] * rq * (1.f + q_s[p1]);
      float q2 = s_q[base + p2] * rq * (1.f + q_s[p2]);
      float k1 = s_k[base + p1] * rk * (1.f + k_s[p1]);
      float k2 = s_k[base + p2] * rk * (1.f + k_s[p2]);
      if (loc < 18) { oq = q1 * c - q2 * s; ok = k1 * c - k2 * s; }
      else          { oq = q1 * s + q2 * c; ok = k1 * s + k2 * c; }
    }
    qp[ob96 + idx] = f2h(oq);
    kp[ob96 + idx] = f2h(ok);
  }
#pragma unroll
  for (int j = 0; j < 5; ++j) {
    int idx = sub + 16 * j;  // 0..79
    float ov = (idx < HD) ? s_v[base + idx] * rv : 0.f;
    vn[ob80 + idx] = f2h(ov);
  }
}

// ---------------- vt[n][h][key] = vn[n][key][h] ----------------
__global__ __launch_bounds__(256) void k_transp_v(const u16* __restrict__ vn, u16* __restrict__ vt) {
  __shared__ u16 tl[64][81];
  int head = blockIdx.y, k0 = blockIdx.x * 64;
  int t = threadIdx.x;
  for (int p = t; p < 64 * 80; p += 256) {
    int r = p / 80, c = p % 80;
    tl[r][c] = vn[((size_t)head * LSEQ + k0 + r) * HP80 + c];
  }
  __syncthreads();
  for (int p = t; p < 80 * 64; p += 256) {
    int hh = p >> 6, kk = p & 63;
    vt[((size_t)head * HP80 + hh) * LSEQ + k0 + kk] = tl[kk][hh];
  }
}

// ---------------- flash attention: per (head, 64 q-rows); 4 waves x 16 rows; K-tile=64 ----------------
__global__ __launch_bounds__(256) void k_flash(
    const u16* __restrict__ qp, const u16* __restrict__ kp,
    const u16* __restrict__ vt, u16* __restrict__ attb) {
  __shared__ __align__(16) u16 sK[64][104];      // [key][hdim] pad 96->104: 2-way banks
  __shared__ __align__(16) u16 sV[80][72];       // [h][key]    pad 64->72:  2-way banks
  __shared__ __align__(16) u16 sP[4][16][72];    // per-wave P roundtrip
  int t = threadIdx.x;
  int l = t & 63, w = t >> 6, lo = l & 15, hi = l >> 4;
  int n = blockIdx.y, qb = blockIdx.x;
  int qrow = qb * 64 + w * 16 + lo;
  const u16* qbase = qp + ((size_t)n * LSEQ + qrow) * HP96 + hi * 8;
  f16x8 aq0 = *(const f16x8*)(qbase);
  f16x8 aq1 = *(const f16x8*)(qbase + 32);
  f16x8 aq2 = *(const f16x8*)(qbase + 64);
  float mrun[4], lrun[4];
  f32x4 oacc[5] = {};
#pragma unroll
  for (int rr = 0; rr < 4; ++rr) { mrun[rr] = -__builtin_inff(); lrun[rr] = 0.f; }
  int sr_ = t >> 2, sq4 = (t & 3) * 24;     // K staging: 4 thr/row
  int vr = t >> 1, vh = (t & 1) * 32;       // V staging: 2 thr/row, t<160
  const u16* kbase = kp + ((size_t)n * LSEQ + sr_) * HP96 + sq4;
  const u16* vbase = vt + ((size_t)n * HP80 + vr) * LSEQ + vh;
  us8 kx0 = *(const us8*)(kbase), kx1 = *(const us8*)(kbase + 8), kx2 = *(const us8*)(kbase + 16);
  us8 vx0 = {}, vx1 = {}, vx2 = {}, vx3 = {};
  if (t < 160) {
    vx0 = *(const us8*)(vbase);      vx1 = *(const us8*)(vbase + 8);
    vx2 = *(const us8*)(vbase + 16); vx3 = *(const us8*)(vbase + 24);
  }
  for (int kt = 0; kt < 64; ++kt) {
    __syncthreads();
    *(us8*)&sK[sr_][sq4] = kx0; *(us8*)&sK[sr_][sq4 + 8] = kx1; *(us8*)&sK[sr_][sq4 + 16] = kx2;
    if (t < 160) {
      *(us8*)&sV[vr][vh] = vx0;      *(us8*)&sV[vr][vh + 8] = vx1;
      *(us8*)&sV[vr][vh + 16] = vx2; *(us8*)&sV[vr][vh + 24] = vx3;
    }
    if (kt < 63) {  // register prefetch of next tile; hides under compute
      const u16* kb = kbase + (size_t)(kt + 1) * 64 * HP96;
      kx0 = *(const us8*)(kb); kx1 = *(const us8*)(kb + 8); kx2 = *(const us8*)(kb + 16);
      if (t < 160) {
        const u16* vb = vbase + (kt + 1) * 64;
        vx0 = *(const us8*)(vb);      vx1 = *(const us8*)(vb + 8);
        vx2 = *(const us8*)(vb + 16); vx3 = *(const us8*)(vb + 24);
      }
    }
    __syncthreads();
    // S = Q K^T for this wave's 16 rows x 64 keys
    f32x4 sacc[4] = {};
#pragma unroll
    for (int c = 0; c < 3; ++c) {
      f16x8 a = (c == 0) ? aq0 : (c == 1) ? aq1 : aq2;
#pragma unroll
      for (int nt = 0; nt < 4; ++nt) {
        f16x8 bk = *(const f16x8*)&sK[lo + 16 * nt][c * 32 + hi * 8];
        sacc[nt] = __builtin_amdgcn_mfma_f32_16x16x32_f16(a, bk, sacc[nt], 0, 0, 0);
      }
    }
    // online softmax; lane holds S[hi*4+rr][lo+16*nt]
    const float L2E = 1.4426950408889634f;
    float mnew[4], alpha[4], rs[4];
#pragma unroll
    for (int rr = 0; rr < 4; ++rr) {
      float mt = fmaxf(fmaxf(sacc[0][rr], sacc[1][rr]), fmaxf(sacc[2][rr], sacc[3][rr]));
#pragma unroll
      for (int msk = 1; msk <= 8; msk <<= 1) mt = fmaxf(mt, __shfl_xor(mt, msk, 64));
      mnew[rr] = fmaxf(mrun[rr], mt);
      alpha[rr] = exp2f((mrun[rr] - mnew[rr]) * L2E);
      mrun[rr] = mnew[rr];
      rs[rr] = 0.f;
    }
#pragma unroll
    for (int nt = 0; nt < 4; ++nt)
#pragma unroll
      for (int rr = 0; rr < 4; ++rr) {
        float p = exp2f((sacc[nt][rr] - mnew[rr]) * L2E);
        sacc[nt][rr] = p;
        rs[rr] += p;
      }
#pragma unroll
    for (int rr = 0; rr < 4; ++rr) {
#pragma unroll
      for (int msk = 1; msk <= 8; msk <<= 1) rs[rr] += __shfl_xor(rs[rr], msk, 64);
      lrun[rr] = lrun[rr] * alpha[rr] + rs[rr];
#pragma unroll
      for (int ht = 0; ht < 5; ++ht) oacc[ht][rr] *= alpha[rr];
    }
    // P -> LDS (wave-private), then PV
#pragma unroll
    for (int nt = 0; nt < 4; ++nt)
#pragma unroll
      for (int rr = 0; rr < 4; ++rr)
        sP[w][hi * 4 + rr][lo + 16 * nt] = f2h(sacc[nt][rr]);
#pragma unroll
    for (int kc = 0; kc < 2; ++kc) {
      f16x8 pa = *(const f16x8*)&sP[w][lo][kc * 32 + hi * 8];
#pragma unroll
      for (int ht = 0; ht < 5; ++ht) {
        f16x8 bv = *(const f16x8*)&sV[lo + 16 * ht][kc * 32 + hi * 8];
        oacc[ht] = __builtin_amdgcn_mfma_f32_16x16x32_f16(pa, bv, oacc[ht], 0, 0, 0);
      }
    }
  }
#pragma unroll
  for (int rr = 0; rr < 4; ++rr) {
    float inv = 1.f / lrun[rr];
    int row = qb * 64 + w * 16 + hi * 4 + rr;
#pragma unroll
    for (int ht = 0; ht < 5; ++ht) {
      int col = lo + 16 * ht;
      if (col < HD)
        attb[(size_t)row * DMODEL + n * HD + col] = f2h(oacc[ht][rr] * inv);
    }
  }
}

extern "C" void kernel_launch(void* const* d_in, const int* in_sizes, int n_in,
                              void* d_out, int out_size, void* d_ws, size_t ws_size,
                              hipStream_t stream) {
  const float* x    = (const float*)d_in[0];
  const float* q_w  = (const float*)d_in[1];
  const float* q_b  = (const float*)d_in[2];
  const float* kv_w = (const float*)d_in[3];
  const float* kv_b = (const float*)d_in[4];
  const float* o_w  = (const float*)d_in[5];
  const float* o_b  = (const float*)d_in[6];
  const float* q_s  = (const float*)d_in[7];
  const float* k_s  = (const float*)d_in[8];
  char* ws = (char*)d_ws;
  // workspace layout (bytes); total high-water = 84,017,152
  u16* xb   = (u16*)(ws + 0);          // 9,437,184   x in f16
  u16* wT   = (u16*)(ws + 9437184);    // 7,962,624   [q_w^T ; kv_w^T] f16 [3456][1152]
  u16* oT   = (u16*)(ws + 17399808);   // 2,654,208   o_w^T f16
  u16* qkvb = (u16*)(ws + 20054016);   // 28,311,552  qkv pre-norm f16 [4096][3456]
  u16* qp   = (u16*)(ws + 48365568);   // 12,582,912  q head-major [16][4096][96]
  u16* kp   = (u16*)(ws + 60948480);   // 12,582,912  k head-major
  u16* vn   = (u16*)(ws + 73531392);   // 10,485,760  v head-major [16][4096][80]
  u16* vt   = (u16*)(ws + 0);          // reuse xb+wT after QKV GEMM: [16][80][4096]
  u16* attb = (u16*)(ws + 20054016);   // reuse qkvb after norm: attn out f16 [4096][1152]

  k_cvt_f16<<<2048, 256, 0, stream>>>(x, xb, LSEQ * DMODEL / 4);
  k_transp_w<<<dim3(36, 36), 256, 0, stream>>>(q_w, wT, DMODEL, DMODEL);
  k_transp_w<<<dim3(72, 36), 256, 0, stream>>>(kv_w, wT + (size_t)DMODEL * DMODEL, DMODEL, 2 * DMODEL);
  k_transp_w<<<dim3(36, 36), 256, 0, stream>>>(o_w, oT, DMODEL, DMODEL);
  k_gemm_bt<false><<<dim3(27, 32), 256, 0, stream>>>(xb, wT, nullptr, qkvb, LSEQ, NQKV, DMODEL);
  k_norm_rope<<<LSEQ, 256, 0, stream>>>(qkvb, q_b, kv_b, q_s, k_s, qp, kp, vn);
  k_transp_v<<<dim3(64, 16), 256, 0, stream>>>(vn, vt);
  k_flash<<<dim3(64, 16), 256, 0, stream>>>(qp, kp, vt, attb);
  k_gemm_bt<true><<<dim3(9, 32), 256, 0, stream>>>(attb, oT, o_b, (float*)d_out, LSEQ, DMODEL, DMODEL);
}

// Round 2
// 313.867 us; speedup vs baseline: 1.3565x; 1.3565x over previous
//
#include <hip/hip_runtime.h>
#include <cstdint>
#include <cstddef>

#define LSEQ 4096
#define DMODEL 1152
#define NH 16
#define HD 72
#define HP96 96
#define HP80 80
#define NQKV 3456

typedef unsigned short u16;
typedef unsigned int u32;
typedef __attribute__((ext_vector_type(4))) float f32x4;
typedef __attribute__((ext_vector_type(4))) u32 u32x4;
typedef _Float16 f16x8 __attribute__((ext_vector_type(8), may_alias));
typedef _Float16 f16x2 __attribute__((ext_vector_type(2), may_alias));
typedef unsigned short us8 __attribute__((ext_vector_type(8), may_alias));
typedef unsigned short us4 __attribute__((ext_vector_type(4), may_alias));

static __device__ __forceinline__ u16 f2h(float f) {
  _Float16 h = (_Float16)f;
  return __builtin_bit_cast(u16, h);
}
static __device__ __forceinline__ float h2f(u16 b) {
  return (float)__builtin_bit_cast(_Float16, b);
}

// ---------------- f32 -> f16 elementwise ----------------
__global__ void k_cvt_f16(const float* __restrict__ src, u16* __restrict__ dst, int n4) {
  int i = blockIdx.x * blockDim.x + threadIdx.x;
  int stride = gridDim.x * blockDim.x;
  for (; i < n4; i += stride) {
    float4 v = ((const float4*)src)[i];
    us4 o; o[0] = f2h(v.x); o[1] = f2h(v.y); o[2] = f2h(v.z); o[3] = f2h(v.w);
    ((us4*)dst)[i] = o;
  }
}

// ---------------- dst[n][k] = (f16) src[k][n]  (weight transpose) ----------------
__global__ void k_transp_w(const float* __restrict__ src, u16* __restrict__ dst, int K, int N) {
  __shared__ float tile[32][33];
  int tx = threadIdx.x & 31, ty = threadIdx.x >> 5;
  int n0 = blockIdx.x * 32, k0 = blockIdx.y * 32;
#pragma unroll
  for (int j = 0; j < 4; ++j)
    tile[ty + j * 8][tx] = src[(size_t)(k0 + ty + j * 8) * N + n0 + tx];
  __syncthreads();
#pragma unroll
  for (int j = 0; j < 4; ++j)
    dst[(size_t)(n0 + ty + j * 8) * K + k0 + tx] = f2h(tile[tx][ty + j * 8]);
}

// ---------------- C[M][N] = A[M][K] @ Bt[N][K]^T (+bias), f16 in, f16/f32 out ----------------
// 128x128 tile, BK=32, 4 waves (2x2 of 64x64), 16x16x32 f16 MFMA.
template <bool OUTF32>
__global__ __launch_bounds__(256) void k_gemm_bt(
    const u16* __restrict__ A, const u16* __restrict__ Bt,
    const float* __restrict__ bias, void* __restrict__ Cout,
    int M, int N, int K) {
  __shared__ __align__(16) u16 sA[128][40];  // +8 pad: 2-way bank aliasing only
  __shared__ __align__(16) u16 sB[128][40];
  int t = threadIdx.x;
  int l = t & 63, w = t >> 6, lo = l & 15, hi = l >> 4;
  int m0 = blockIdx.y * 128, n0 = blockIdx.x * 128;
  int wm = (w >> 1) * 64, wn = (w & 1) * 64;
  int sr = t >> 1, sh = (t & 1) * 16;
  const u16* pa = A + (size_t)(m0 + sr) * K + sh;
  const u16* pb = Bt + (size_t)(n0 + sr) * K + sh;
  f32x4 acc[4][4] = {};
  us8 ra0 = *(const us8*)(pa), ra1 = *(const us8*)(pa + 8);
  us8 rb0 = *(const us8*)(pb), rb1 = *(const us8*)(pb + 8);
  int nk = K >> 5;
  for (int ks = 0; ks < nk; ++ks) {
    __syncthreads();
    *(us8*)&sA[sr][sh] = ra0; *(us8*)&sA[sr][sh + 8] = ra1;
    *(us8*)&sB[sr][sh] = rb0; *(us8*)&sB[sr][sh + 8] = rb1;
    if (ks + 1 < nk) {  // prefetch next tile into regs; latency hides under MFMA
      int off = (ks + 1) * 32;
      ra0 = *(const us8*)(pa + off); ra1 = *(const us8*)(pa + off + 8);
      rb0 = *(const us8*)(pb + off); rb1 = *(const us8*)(pb + off + 8);
    }
    __syncthreads();
    f16x8 af[4], bf[4];
#pragma unroll
    for (int mi = 0; mi < 4; ++mi) af[mi] = *(const f16x8*)&sA[wm + mi * 16 + lo][hi * 8];
#pragma unroll
    for (int ni = 0; ni < 4; ++ni) bf[ni] = *(const f16x8*)&sB[wn + ni * 16 + lo][hi * 8];
#pragma unroll
    for (int mi = 0; mi < 4; ++mi)
#pragma unroll
      for (int ni = 0; ni < 4; ++ni)
        acc[mi][ni] = __builtin_amdgcn_mfma_f32_16x16x32_f16(af[mi], bf[ni], acc[mi][ni], 0, 0, 0);
  }
#pragma unroll
  for (int mi = 0; mi < 4; ++mi)
#pragma unroll
    for (int ni = 0; ni < 4; ++ni) {
      int row = m0 + wm + mi * 16 + hi * 4;
      int col = n0 + wn + ni * 16 + lo;
      float bv = bias ? bias[col] : 0.0f;
#pragma unroll
      for (int rr = 0; rr < 4; ++rr) {
        float v = acc[mi][ni][rr] + bv;
        if (OUTF32) ((float*)Cout)[(size_t)(row + rr) * N + col] = v;
        else        ((u16*)Cout)[(size_t)(row + rr) * N + col] = f2h(v);
      }
    }
}

// ---------------- per-token: +bias, per-head RMSNorm, 2D RoPE, scatter to head-major ----------------
__global__ __launch_bounds__(256) void k_norm_rope(
    const u16* __restrict__ qkv,
    const float* __restrict__ q_b, const float* __restrict__ kv_b,
    const float* __restrict__ q_s, const float* __restrict__ k_s,
    u16* __restrict__ qp, u16* __restrict__ kp, u16* __restrict__ vn) {
  __shared__ float s_q[DMODEL], s_k[DMODEL], s_v[DMODEL];
  __shared__ float cs[4][18];  // [cr, sr, cc, sc]
  int t = threadIdx.x;
  int tok = blockIdx.x;
  if (t < 36) {
    int i = t < 18 ? t : t - 18;
    float f = exp2f(-(float)i * (6.6438561897747247f / 9.0f));  // 100^(-i/9)
    float pos = (t < 18) ? (float)(tok >> 6) : (float)(tok & 63);
    float s, c;
    sincosf(pos * f, &s, &c);
    if (t < 18) { cs[0][i] = c; cs[1][i] = s; }
    else        { cs[2][i] = c; cs[3][i] = s; }
  }
  const u16* rowp = qkv + (size_t)tok * NQKV;
  for (int idx = t; idx < DMODEL; idx += 256) {
    s_q[idx] = h2f(rowp[idx]) + q_b[idx];
    s_k[idx] = h2f(rowp[DMODEL + idx]) + kv_b[idx];
    s_v[idx] = h2f(rowp[2 * DMODEL + idx]) + kv_b[DMODEL + idx];
  }
  __syncthreads();
  int h = t >> 4, sub = t & 15;  // 16 threads per head
  int base = h * HD;
  float aq = 0, ak = 0, av = 0;
#pragma unroll
  for (int j = 0; j < 5; ++j) {
    int idx = sub + 16 * j;
    if (idx < HD) {
      float a = s_q[base + idx], b = s_k[base + idx], c = s_v[base + idx];
      aq += a * a; ak += b * b; av += c * c;
    }
  }
#pragma unroll
  for (int m = 1; m <= 8; m <<= 1) {
    aq += __shfl_xor(aq, m, 64);
    ak += __shfl_xor(ak, m, 64);
    av += __shfl_xor(av, m, 64);
  }
  float rq = rsqrtf(aq / 72.f + 1e-6f);
  float rk = rsqrtf(ak / 72.f + 1e-6f);
  float rv = rsqrtf(av / 72.f + 1e-6f);
  size_t ob96 = ((size_t)h * LSEQ + tok) * HP96;
  size_t ob80 = ((size_t)h * LSEQ + tok) * HP80;
#pragma unroll
  for (int j = 0; j < 6; ++j) {
    int idx = sub + 16 * j;  // 0..95
    float oq = 0.f, ok = 0.f;
    if (idx < HD) {
      int sec = idx >= 36;          // 0: rows angle, 1: cols angle
      int loc = idx - sec * 36;
      int i = loc >= 18 ? loc - 18 : loc;
      float c = cs[sec * 2 + 0][i], s = cs[sec * 2 + 1][i];
      int p1 = sec * 36 + i, p2 = p1 + 18;
      float q1 = s_q[base + p1] * rq * (1.f + q_s[p1]);
      float q2 = s_q[base + p2] * rq * (1.f + q_s[p2]);
      float k1 = s_k[base + p1] * rk * (1.f + k_s[p1]);
      float k2 = s_k[base + p2] * rk * (1.f + k_s[p2]);
      if (loc < 18) { oq = q1 * c - q2 * s; ok = k1 * c - k2 * s; }
      else          { oq = q1 * s + q2 * c; ok = k1 * s + k2 * c; }
    }
    qp[ob96 + idx] = f2h(oq);
    kp[ob96 + idx] = f2h(ok);
  }
#pragma unroll
  for (int j = 0; j < 5; ++j) {
    int idx = sub + 16 * j;  // 0..79
    float ov = (idx < HD) ? s_v[base + idx] * rv : 0.f;
    vn[ob80 + idx] = f2h(ov);
  }
}

// ---------------- vt[n][h][key] = vn[n][key][h] ----------------
__global__ __launch_bounds__(256) void k_transp_v(const u16* __restrict__ vn, u16* __restrict__ vt) {
  __shared__ u16 tl[64][81];
  int head = blockIdx.y, k0 = blockIdx.x * 64;
  int t = threadIdx.x;
  for (int p = t; p < 64 * 80; p += 256) {
    int r = p / 80, c = p % 80;
    tl[r][c] = vn[((size_t)head * LSEQ + k0 + r) * HP80 + c];
  }
  __syncthreads();
  for (int p = t; p < 80 * 64; p += 256) {
    int hh = p >> 6, kk = p & 63;
    vt[((size_t)head * HP80 + hh) * LSEQ + k0 + kk] = tl[kk][hh];
  }
}

// key -> permuted LDS slot so that packed-P registers are directly a valid
// B-fragment: slot s(k) = 32*(k>>5) + 8*((k>>2)&3) + 4*((k>>4)&1) + (k&3)
static __device__ __forceinline__ int v_slot(int k) {
  return (k & 32) + (((k >> 2) & 3) << 3) + (((k >> 4) & 1) << 2) + (k & 3);
}

// ---------------- flash attention, swapped-QK in-register softmax ----------------
// per (head, 64 q-rows); 4 waves x 16 q-rows; K-tile = 64.
// S = mfma(K_frag, Q_frag): lane holds S[key=16nt+hi*4+rr][q=lo] -> row-softmax is
// lane-local (+2 shfl over hi groups). P packed via cvt_pkrtz feeds PV's B operand
// directly; V staged key-permuted (v_slot) so no cross-lane P movement is needed.
// PV computes out^T = mfma(A=V^T, B=P): lane ends with oacc[ht][rr] = out[h][q=lo].
__global__ __launch_bounds__(256) void k_flash(
    const u16* __restrict__ qp, const u16* __restrict__ kp,
    const u16* __restrict__ vt, u16* __restrict__ attb) {
  __shared__ __align__(16) u16 sK[64][104];      // [key][hdim] pad 96->104
  __shared__ __align__(16) u16 sVp[80][72];      // [h][slot]   pad 64->72
  int t = threadIdx.x;
  int l = t & 63, w = t >> 6, lo = l & 15, hi = l >> 4;
  int n = blockIdx.y, qb = blockIdx.x;
  int qrow = qb * 64 + w * 16 + lo;
  const u16* qbase = qp + ((size_t)n * LSEQ + qrow) * HP96 + hi * 8;
  f16x8 aq0 = *(const f16x8*)(qbase);
  f16x8 aq1 = *(const f16x8*)(qbase + 32);
  f16x8 aq2 = *(const f16x8*)(qbase + 64);
  float mrun = -__builtin_inff(), lrun = 0.f;
  f32x4 oacc[5] = {};
  int sr_ = t >> 2, sq4 = (t & 3) * 24;     // K staging: 4 thr/row
  int vr = t >> 1, vh = (t & 1) * 32;       // V staging: 2 thr/row, t<160
  const u16* kbase = kp + ((size_t)n * LSEQ + sr_) * HP96 + sq4;
  const u16* vbase = vt + ((size_t)n * HP80 + vr) * LSEQ + vh;
  // precompute permuted slots for this thread's 8 aligned 4-key groups
  int vs[8];
#pragma unroll
  for (int c = 0; c < 8; ++c) vs[c] = v_slot(vh + 4 * c);
  us8 kx0 = *(const us8*)(kbase), kx1 = *(const us8*)(kbase + 8), kx2 = *(const us8*)(kbase + 16);
  us8 vx0 = {}, vx1 = {}, vx2 = {}, vx3 = {};
  if (t < 160) {
    vx0 = *(const us8*)(vbase);      vx1 = *(const us8*)(vbase + 8);
    vx2 = *(const us8*)(vbase + 16); vx3 = *(const us8*)(vbase + 24);
  }
  const float L2E = 1.4426950408889634f;
  for (int kt = 0; kt < 64; ++kt) {
    __syncthreads();
    *(us8*)&sK[sr_][sq4] = kx0; *(us8*)&sK[sr_][sq4 + 8] = kx1; *(us8*)&sK[sr_][sq4 + 16] = kx2;
    if (t < 160) {
      us8 vv[4] = {vx0, vx1, vx2, vx3};
#pragma unroll
      for (int c = 0; c < 4; ++c) {
        us4 lo4 = __builtin_shufflevector(vv[c], vv[c], 0, 1, 2, 3);
        us4 hi4 = __builtin_shufflevector(vv[c], vv[c], 4, 5, 6, 7);
        *(us4*)&sVp[vr][vs[2 * c]]     = lo4;
        *(us4*)&sVp[vr][vs[2 * c + 1]] = hi4;
      }
    }
    if (kt < 63) {  // register prefetch of next tile; hides under compute
      const u16* kb = kbase + (size_t)(kt + 1) * 64 * HP96;
      kx0 = *(const us8*)(kb); kx1 = *(const us8*)(kb + 8); kx2 = *(const us8*)(kb + 16);
      if (t < 160) {
        const u16* vb = vbase + (kt + 1) * 64;
        vx0 = *(const us8*)(vb);      vx1 = *(const us8*)(vb + 8);
        vx2 = *(const us8*)(vb + 16); vx3 = *(const us8*)(vb + 24);
      }
    }
    __syncthreads();
    // S^T: lane holds S[key = 16*nt + hi*4 + rr][q = lo]
    f32x4 sacc[4] = {};
#pragma unroll
    for (int c = 0; c < 3; ++c) {
      f16x8 a = (c == 0) ? aq0 : (c == 1) ? aq1 : aq2;
#pragma unroll
      for (int nt = 0; nt < 4; ++nt) {
        f16x8 bk = *(const f16x8*)&sK[lo + 16 * nt][c * 32 + hi * 8];
        sacc[nt] = __builtin_amdgcn_mfma_f32_16x16x32_f16(bk, a, sacc[nt], 0, 0, 0);
      }
    }
    // lane-local online softmax for q = lo
    float mt = fmaxf(fmaxf(sacc[0][0], sacc[0][1]), fmaxf(sacc[0][2], sacc[0][3]));
#pragma unroll
    for (int nt = 1; nt < 4; ++nt)
      mt = fmaxf(mt, fmaxf(fmaxf(sacc[nt][0], sacc[nt][1]), fmaxf(sacc[nt][2], sacc[nt][3])));
    mt = fmaxf(mt, __shfl_xor(mt, 16, 64));
    mt = fmaxf(mt, __shfl_xor(mt, 32, 64));
    float mnew = fmaxf(mrun, mt);
    float alpha = exp2f((mrun - mnew) * L2E);
    mrun = mnew;
    float p[4][4];
    float rs = 0.f;
#pragma unroll
    for (int nt = 0; nt < 4; ++nt)
#pragma unroll
      for (int rr = 0; rr < 4; ++rr) {
        float e = exp2f((sacc[nt][rr] - mnew) * L2E);
        p[nt][rr] = e;
        rs += e;
      }
    rs += __shfl_xor(rs, 16, 64);
    rs += __shfl_xor(rs, 32, 64);
    lrun = lrun * alpha + rs;
#pragma unroll
    for (int ht = 0; ht < 5; ++ht)
#pragma unroll
      for (int rr = 0; rr < 4; ++rr) oacc[ht][rr] *= alpha;
    // pack P -> f16 pairs; registers are directly PV's B-fragment (keys permuted)
    u32 wpk[4][2];
#pragma unroll
    for (int nt = 0; nt < 4; ++nt) {
      wpk[nt][0] = __builtin_bit_cast(u32, __builtin_amdgcn_cvt_pkrtz(p[nt][0], p[nt][1]));
      wpk[nt][1] = __builtin_bit_cast(u32, __builtin_amdgcn_cvt_pkrtz(p[nt][2], p[nt][3]));
    }
#pragma unroll
    for (int kc = 0; kc < 2; ++kc) {
      u32x4 bwords = {wpk[2 * kc][0], wpk[2 * kc][1], wpk[2 * kc + 1][0], wpk[2 * kc + 1][1]};
      f16x8 pb = __builtin_bit_cast(f16x8, bwords);
#pragma unroll
      for (int ht = 0; ht < 5; ++ht) {
        f16x8 av = *(const f16x8*)&sVp[ht * 16 + lo][kc * 32 + hi * 8];
        oacc[ht] = __builtin_amdgcn_mfma_f32_16x16x32_f16(av, pb, oacc[ht], 0, 0, 0);
      }
    }
  }
  float inv = 1.f / lrun;
  int row = qb * 64 + w * 16 + lo;
#pragma unroll
  for (int ht = 0; ht < 5; ++ht)
#pragma unroll
    for (int rr = 0; rr < 4; ++rr) {
      int h = ht * 16 + hi * 4 + rr;
      if (h < HD)
        attb[(size_t)row * DMODEL + n * HD + h] = f2h(oacc[ht][rr] * inv);
    }
}

extern "C" void kernel_launch(void* const* d_in, const int* in_sizes, int n_in,
                              void* d_out, int out_size, void* d_ws, size_t ws_size,
                              hipStream_t stream) {
  const float* x    = (const float*)d_in[0];
  const float* q_w  = (const float*)d_in[1];
  const float* q_b  = (const float*)d_in[2];
  const float* kv_w = (const float*)d_in[3];
  const float* kv_b = (const float*)d_in[4];
  const float* o_w  = (const float*)d_in[5];
  const float* o_b  = (const float*)d_in[6];
  const float* q_s  = (const float*)d_in[7];
  const float* k_s  = (const float*)d_in[8];
  char* ws = (char*)d_ws;
  // workspace layout (bytes); total high-water = 84,017,152
  u16* xb   = (u16*)(ws + 0);          // 9,437,184   x in f16
  u16* wT   = (u16*)(ws + 9437184);    // 7,962,624   [q_w^T ; kv_w^T] f16 [3456][1152]
  u16* oT   = (u16*)(ws + 17399808);   // 2,654,208   o_w^T f16
  u16* qkvb = (u16*)(ws + 20054016);   // 28,311,552  qkv pre-norm f16 [4096][3456]
  u16* qp   = (u16*)(ws + 48365568);   // 12,582,912  q head-major [16][4096][96]
  u16* kp   = (u16*)(ws + 60948480);   // 12,582,912  k head-major
  u16* vn   = (u16*)(ws + 73531392);   // 10,485,760  v head-major [16][4096][80]
  u16* vt   = (u16*)(ws + 0);          // reuse xb+wT after QKV GEMM: [16][80][4096]
  u16* attb = (u16*)(ws + 20054016);   // reuse qkvb after norm: attn out f16 [4096][1152]

  k_cvt_f16<<<2048, 256, 0, stream>>>(x, xb, LSEQ * DMODEL / 4);
  k_transp_w<<<dim3(36, 36), 256, 0, stream>>>(q_w, wT, DMODEL, DMODEL);
  k_transp_w<<<dim3(72, 36), 256, 0, stream>>>(kv_w, wT + (size_t)DMODEL * DMODEL, DMODEL, 2 * DMODEL);
  k_transp_w<<<dim3(36, 36), 256, 0, stream>>>(o_w, oT, DMODEL, DMODEL);
  k_gemm_bt<false><<<dim3(27, 32), 256, 0, stream>>>(xb, wT, nullptr, qkvb, LSEQ, NQKV, DMODEL);
  k_norm_rope<<<LSEQ, 256, 0, stream>>>(qkvb, q_b, kv_b, q_s, k_s, qp, kp, vn);
  k_transp_v<<<dim3(64, 16), 256, 0, stream>>>(vn, vt);
  k_flash<<<dim3(64, 16), 256, 0, stream>>>(qp, kp, vt, attb);
  k_gemm_bt<true><<<dim3(9, 32), 256, 0, stream>>>(attb, oT, o_b, (float*)d_out, LSEQ, DMODEL, DMODEL);
}